// Round 2
// baseline (513.225 us; speedup 1.0000x reference)
//
#include <hip/hip_runtime.h>
#include <stdint.h>

typedef unsigned short u16;
typedef float    f32x4  __attribute__((ext_vector_type(4)));
typedef __bf16   bf16x8 __attribute__((ext_vector_type(8)));
typedef u16      u16x8  __attribute__((ext_vector_type(8)));
typedef u16      u16x4  __attribute__((ext_vector_type(4)));
typedef float    f32x4v __attribute__((ext_vector_type(4)));

#define B_SZ   2
#define S_LEN  2048
#define HDIM   2048
#define NH_    16
#define NKV_   2
#define HD_    128
#define M_ROWS 4096   // B*S
#define NQKV   2560   // (NH + 2*NKV) * HD

static __device__ __forceinline__ u16 f2bf(float f) {
    uint32_t u = __builtin_bit_cast(uint32_t, f);
    uint32_t r = (u + 0x7fffu + ((u >> 16) & 1u)) >> 16;
    return (u16)r;
}
static __device__ __forceinline__ float bf2f(u16 b) {
    uint32_t u = ((uint32_t)b) << 16;
    return __builtin_bit_cast(float, u);
}
static __device__ __forceinline__ void gload_lds16(const void* g, void* l) {
    __builtin_amdgcn_global_load_lds((__attribute__((address_space(1))) void*)(g),
                                     (__attribute__((address_space(3))) void*)(l),
                                     16, 0, 0);
}

// ---------------- elementwise converts ----------------
__global__ void cvt_f32_bf16(const float* __restrict__ in, u16* __restrict__ out, int n4) {
    int i = blockIdx.x * blockDim.x + threadIdx.x;
    if (i >= n4) return;
    f32x4v v = ((const f32x4v*)in)[i];
    u16x4 o;
    o[0] = f2bf(v[0]); o[1] = f2bf(v[1]); o[2] = f2bf(v[2]); o[3] = f2bf(v[3]);
    ((u16x4*)out)[i] = o;
}

__global__ void concat_bias(const float* __restrict__ qb, const float* __restrict__ kb,
                            const float* __restrict__ vb, float* __restrict__ out) {
    int i = blockIdx.x * blockDim.x + threadIdx.x;
    if (i >= NQKV) return;
    if (i < 2048)       out[i] = qb[i];
    else if (i < 2304)  out[i] = kb[i - 2048];
    else                out[i] = vb[i - 2304];
}

__global__ void rope_table(float* __restrict__ tc, float* __restrict__ ts) {
    int p = blockIdx.x;
    int d = threadIdx.x;   // 64 threads
    // inv_freq = 10000^(-d/64) = exp(-ln(10000)*d/64)
    float inv = expf(-(float)d * 0.14391156831212787f);
    float ang = (float)p * inv;
    float s, c;
    sincosf(ang, &s, &c);
    tc[p * 64 + d] = c;
    ts[p * 64 + d] = s;
}

// ---------------- GEMM: C[m,n] = sum_k A[m,k]*W[n,k] (+bias[n]) ----------------
// m97-style: 128x128 tile, BK=32, 4 waves (2x2 of 64x64), 16x16x32 bf16 MFMA.
template <typename OutT, bool HAS_BIAS>
__global__ __launch_bounds__(256) void gemm_bt(const u16* __restrict__ A,
                                               const u16* __restrict__ W,
                                               const float* __restrict__ bias,
                                               OutT* __restrict__ C,
                                               int M, int N, int K) {
    __shared__ u16 sA[128 * 32];
    __shared__ u16 sB[128 * 32];
    const int tid = threadIdx.x;
    const int lane = tid & 63;
    const int w = tid >> 6;
    const int wr = w >> 1, wc = w & 1;
    const int l15 = lane & 15, l4 = lane >> 4;
    const int brow = blockIdx.y * 128;
    const int bcol = blockIdx.x * 128;

    f32x4 acc[4][4];
#pragma unroll
    for (int m = 0; m < 4; ++m)
#pragma unroll
        for (int n = 0; n < 4; ++n) acc[m][n] = (f32x4){0.f, 0.f, 0.f, 0.f};

    const int nk = K >> 5;
    for (int kt = 0; kt < nk; ++kt) {
        __syncthreads();
#pragma unroll
        for (int i = 0; i < 2; ++i) {
            int e = i * 2048 + tid * 8;
            int row = e >> 5, col = e & 31;
            gload_lds16(A + (size_t)(brow + row) * K + kt * 32 + col, &sA[e]);
            gload_lds16(W + (size_t)(bcol + row) * K + kt * 32 + col, &sB[e]);
        }
        __syncthreads();
        bf16x8 af[4], bfr[4];
#pragma unroll
        for (int m = 0; m < 4; ++m)
            af[m] = *(const bf16x8*)&sA[(wr * 64 + m * 16 + l15) * 32 + l4 * 8];
#pragma unroll
        for (int n = 0; n < 4; ++n)
            bfr[n] = *(const bf16x8*)&sB[(wc * 64 + n * 16 + l15) * 32 + l4 * 8];
#pragma unroll
        for (int m = 0; m < 4; ++m)
#pragma unroll
            for (int n = 0; n < 4; ++n)
                acc[m][n] = __builtin_amdgcn_mfma_f32_16x16x32_bf16(af[m], bfr[n], acc[m][n], 0, 0, 0);
    }

#pragma unroll
    for (int m = 0; m < 4; ++m) {
#pragma unroll
        for (int n = 0; n < 4; ++n) {
            int cn = bcol + wc * 64 + n * 16 + l15;
            float bv = 0.f;
            if constexpr (HAS_BIAS) bv = bias[cn];
#pragma unroll
            for (int i = 0; i < 4; ++i) {
                int r = brow + wr * 64 + m * 16 + l4 * 4 + i;
                float v = acc[m][n][i] + bv;
                if constexpr (sizeof(OutT) == 2) {
                    C[(size_t)r * N + cn] = (OutT)f2bf(v);
                } else {
                    C[(size_t)r * N + cn] = v;
                }
            }
        }
    }
}

// ---------------- RoPE + layout: qkv[B*S, 2560] -> Qr[B,NH,S,D], Kr/Vr[B,NKV,S,D] ----------------
__global__ void rope_apply(const u16* __restrict__ qkv, const int* __restrict__ pos,
                           const float* __restrict__ tc, const float* __restrict__ ts,
                           u16* __restrict__ Qr, u16* __restrict__ Kr, u16* __restrict__ Vr) {
    int idx = blockIdx.x * blockDim.x + threadIdx.x;
    if (idx >= M_ROWS * 20 * 64) return;
    int d = idx & 63;
    int sec = (idx >> 6) % 20;
    int row = idx / (20 * 64);
    int b = row >> 11, s = row & 2047;
    int p = pos[row];
    const u16* q = qkv + (size_t)row * NQKV;
    if (sec < 16) {
        float c = tc[p * 64 + d], sn = ts[p * 64 + d];
        float x1 = bf2f(q[sec * 128 + d]);
        float x2 = bf2f(q[sec * 128 + d + 64]);
        size_t o = (((size_t)(b * NH_ + sec)) * S_LEN + s) * HD_ + d;
        Qr[o] = f2bf(x1 * c - x2 * sn);
        Qr[o + 64] = f2bf(x2 * c + x1 * sn);
    } else if (sec < 18) {
        int hk = sec - 16;
        float c = tc[p * 64 + d], sn = ts[p * 64 + d];
        float x1 = bf2f(q[2048 + hk * 128 + d]);
        float x2 = bf2f(q[2048 + hk * 128 + d + 64]);
        size_t o = (((size_t)(b * NKV_ + hk)) * S_LEN + s) * HD_ + d;
        Kr[o] = f2bf(x1 * c - x2 * sn);
        Kr[o + 64] = f2bf(x2 * c + x1 * sn);
    } else {
        int hv = sec - 18;
        size_t o = (((size_t)(b * NKV_ + hv)) * S_LEN + s) * HD_ + d;
        Vr[o] = q[2304 + hv * 128 + d];
        Vr[o + 64] = q[2304 + hv * 128 + d + 64];
    }
}

// ---------------- flash attention (causal, GQA) ----------------
// grid: (S/64, B*NH). 4 waves/block, each wave owns 16 q-rows. KV tile = 32.
#define QB 64
#define KVB 32
#define VT_STRIDE 40   // padded: row stride 80B -> l15*20 mod 32 has period 8 -> 2-way (free)
__global__ __launch_bounds__(256) void attn_kernel(const u16* __restrict__ Qr,
                                                   const u16* __restrict__ Kr,
                                                   const u16* __restrict__ Vr,
                                                   u16* __restrict__ Ao) {
    __shared__ u16 sK[KVB * HD_];         // XOR-swizzled rows [key][d]
    __shared__ u16 sVt[HD_ * VT_STRIDE];  // transposed [d][key], padded stride
    __shared__ u16 sP[4][16 * KVB];       // per-wave P tile

    const int tid = threadIdx.x;
    const int lane = tid & 63;
    const int w = tid >> 6;
    const int l15 = lane & 15;
    const int l4 = lane >> 4;

    const int qb = blockIdx.x;
    const int bh = blockIdx.y;
    const int b = bh >> 4;
    const int h = bh & 15;
    const int kvh = h >> 3;

    const int qr0 = qb * QB + w * 16;
    const size_t qbase = (((size_t)(b * NH_ + h)) * S_LEN + qr0 + l15) * HD_;
    bf16x8 qf[4];
#pragma unroll
    for (int c = 0; c < 4; ++c)
        qf[c] = *(const bf16x8*)(Qr + qbase + c * 32 + l4 * 8);

    const size_t kvbase = ((size_t)(b * NKV_ + kvh)) * S_LEN * HD_;

    f32x4 oa[8];
#pragma unroll
    for (int c = 0; c < 8; ++c) oa[c] = (f32x4){0.f, 0.f, 0.f, 0.f};
    float mrow[4], lrow[4];
#pragma unroll
    for (int i = 0; i < 4; ++i) { mrow[i] = -1e30f; lrow[i] = 0.f; }

    const int nt = 2 * qb + 2;
    const float scale = 0.08838834764831845f;  // 1/sqrt(128)

    for (int t = 0; t < nt; ++t) {
        const int k0 = t * KVB;
        __syncthreads();
        // stage K via global_load_lds, pre-swizzled source (G4 XOR swizzle)
#pragma unroll
        for (int i = 0; i < 2; ++i) {
            int e = i * 2048 + tid * 8;
            int L = e * 2;
            int key = L >> 8;
            int inner = (L & 255) ^ ((key & 7) << 4);
            gload_lds16(Kr + kvbase + (size_t)(k0 + key) * HD_ + (inner >> 1), &sK[e]);
        }
        // stage V transposed (reg-staged)
        {
            int key = tid & 31;
            int d0 = (tid >> 5) * 16;
            const u16* src = Vr + kvbase + (size_t)(k0 + key) * HD_ + d0;
            u16x8 v0 = *(const u16x8*)(src);
            u16x8 v1 = *(const u16x8*)(src + 8);
#pragma unroll
            for (int j = 0; j < 8; ++j) sVt[(d0 + j) * VT_STRIDE + key] = v0[j];
#pragma unroll
            for (int j = 0; j < 8; ++j) sVt[(d0 + 8 + j) * VT_STRIDE + key] = v1[j];
        }
        __syncthreads();
        if (k0 > qr0 + 15) continue;  // wave-uniform: tile fully masked for this wave

        // QK^T -> 2 fragments of 16q x 16k
        f32x4 sf[2];
#pragma unroll
        for (int kt2 = 0; kt2 < 2; ++kt2) {
            f32x4 f = (f32x4){0.f, 0.f, 0.f, 0.f};
#pragma unroll
            for (int c = 0; c < 4; ++c) {
                int key = kt2 * 16 + l15;
                int addr = (key * 256 + c * 64 + l4 * 16) ^ ((key & 7) << 4);
                bf16x8 kf = *(const bf16x8*)((const char*)sK + addr);
                f = __builtin_amdgcn_mfma_f32_16x16x32_bf16(qf[c], kf, f, 0, 0, 0);
            }
            sf[kt2] = f;
        }
        // scale + causal mask + row max
        float pm[4];
#pragma unroll
        for (int i = 0; i < 4; ++i) pm[i] = -1e30f;
#pragma unroll
        for (int kt2 = 0; kt2 < 2; ++kt2) {
            int kk = k0 + kt2 * 16 + l15;
#pragma unroll
            for (int i = 0; i < 4; ++i) {
                int qq = qr0 + l4 * 4 + i;
                float v = sf[kt2][i] * scale;
                v = (kk <= qq) ? v : -1e30f;
                sf[kt2][i] = v;
                pm[i] = fmaxf(pm[i], v);
            }
        }
#pragma unroll
        for (int off = 1; off < 16; off <<= 1)
#pragma unroll
            for (int i = 0; i < 4; ++i) pm[i] = fmaxf(pm[i], __shfl_xor(pm[i], off));
        // online softmax update
        float al[4], rs[4];
#pragma unroll
        for (int i = 0; i < 4; ++i) {
            float mn = fmaxf(mrow[i], pm[i]);
            al[i] = __expf(mrow[i] - mn);
            mrow[i] = mn;
        }
#pragma unroll
        for (int kt2 = 0; kt2 < 2; ++kt2)
#pragma unroll
            for (int i = 0; i < 4; ++i) sf[kt2][i] = __expf(sf[kt2][i] - mrow[i]);
#pragma unroll
        for (int i = 0; i < 4; ++i) rs[i] = sf[0][i] + sf[1][i];
#pragma unroll
        for (int off = 1; off < 16; off <<= 1)
#pragma unroll
            for (int i = 0; i < 4; ++i) rs[i] += __shfl_xor(rs[i], off);
#pragma unroll
        for (int i = 0; i < 4; ++i) lrow[i] = lrow[i] * al[i] + rs[i];
#pragma unroll
        for (int c = 0; c < 8; ++c)
#pragma unroll
            for (int i = 0; i < 4; ++i) oa[c][i] *= al[i];
        // P -> LDS (bf16), C-layout scatter
#pragma unroll
        for (int kt2 = 0; kt2 < 2; ++kt2)
#pragma unroll
            for (int i = 0; i < 4; ++i)
                sP[w][(l4 * 4 + i) * KVB + kt2 * 16 + l15] = f2bf(sf[kt2][i]);
        // PV
        bf16x8 paf = *(const bf16x8*)&sP[w][l15 * KVB + l4 * 8];
#pragma unroll
        for (int c2 = 0; c2 < 8; ++c2) {
            bf16x8 vf = *(const bf16x8*)&sVt[(c2 * 16 + l15) * VT_STRIDE + l4 * 8];
            oa[c2] = __builtin_amdgcn_mfma_f32_16x16x32_bf16(paf, vf, oa[c2], 0, 0, 0);
        }
    }
    // epilogue: divide by l, store to Ao[B*S, NH*HD]
#pragma unroll
    for (int i = 0; i < 4; ++i) {
        float inv = 1.0f / lrow[i];
        int qrow = qr0 + l4 * 4 + i;
        size_t rbase = ((size_t)(b * S_LEN) + qrow) * (size_t)(NH_ * HD_) + h * HD_;
#pragma unroll
        for (int c2 = 0; c2 < 8; ++c2)
            Ao[rbase + c2 * 16 + l15] = f2bf(oa[c2][i] * inv);
    }
}

// ---------------- launch ----------------
extern "C" void kernel_launch(void* const* d_in, const int* in_sizes, int n_in,
                              void* d_out, int out_size, void* d_ws, size_t ws_size,
                              hipStream_t stream) {
    (void)in_sizes; (void)n_in; (void)out_size; (void)ws_size;
    const float* hs  = (const float*)d_in[0];
    const int*   pos = (const int*)d_in[1];
    const float* q_w = (const float*)d_in[2];
    const float* q_b = (const float*)d_in[3];
    const float* k_w = (const float*)d_in[4];
    const float* k_b = (const float*)d_in[5];
    const float* v_w = (const float*)d_in[6];
    const float* v_b = (const float*)d_in[7];
    const float* o_w = (const float*)d_in[8];
    float* out = (float*)d_out;

    char* ws = (char*)d_ws;
    u16* hsb = (u16*)ws;   ws += (size_t)M_ROWS * HDIM * 2;         // 16.8 MB
    u16* wcat = (u16*)ws;  ws += (size_t)NQKV * HDIM * 2;           // 10.5 MB
    u16* owb = (u16*)ws;   ws += (size_t)HDIM * HDIM * 2;           // 8.4 MB
    float* bcat = (float*)ws; ws += (size_t)NQKV * 4;
    float* tc = (float*)ws;   ws += (size_t)S_LEN * 64 * 4;
    float* ts = (float*)ws;   ws += (size_t)S_LEN * 64 * 4;
    u16* qkv = (u16*)ws;   ws += (size_t)M_ROWS * NQKV * 2;         // 21 MB
    u16* Kr = (u16*)ws;    ws += (size_t)B_SZ * NKV_ * S_LEN * HD_ * 2;
    u16* Vr = (u16*)ws;    ws += (size_t)B_SZ * NKV_ * S_LEN * HD_ * 2;
    u16* Qr = hsb;   // alias: hsb dead after QKV GEMM
    u16* Ao = qkv;   // alias: qkv dead after rope_apply

    // converts
    cvt_f32_bf16<<<(M_ROWS * HDIM / 4 + 255) / 256, 256, 0, stream>>>(hs, hsb, M_ROWS * HDIM / 4);
    cvt_f32_bf16<<<(2048 * 2048 / 4 + 255) / 256, 256, 0, stream>>>(q_w, wcat, 2048 * 2048 / 4);
    cvt_f32_bf16<<<(256 * 2048 / 4 + 255) / 256, 256, 0, stream>>>(k_w, wcat + (size_t)2048 * 2048, 256 * 2048 / 4);
    cvt_f32_bf16<<<(256 * 2048 / 4 + 255) / 256, 256, 0, stream>>>(v_w, wcat + (size_t)2304 * 2048, 256 * 2048 / 4);
    cvt_f32_bf16<<<(2048 * 2048 / 4 + 255) / 256, 256, 0, stream>>>(o_w, owb, 2048 * 2048 / 4);
    concat_bias<<<(NQKV + 255) / 256, 256, 0, stream>>>(q_b, k_b, v_b, bcat);
    rope_table<<<S_LEN, 64, 0, stream>>>(tc, ts);

    // QKV projection
    gemm_bt<u16, true><<<dim3(NQKV / 128, M_ROWS / 128), 256, 0, stream>>>(
        hsb, wcat, bcat, qkv, M_ROWS, NQKV, HDIM);

    // RoPE + layout
    rope_apply<<<(M_ROWS * 20 * 64 + 255) / 256, 256, 0, stream>>>(qkv, pos, tc, ts, Qr, Kr, Vr);

    // attention
    attn_kernel<<<dim3(S_LEN / QB, B_SZ * NH_), 256, 0, stream>>>(Qr, Kr, Vr, Ao);

    // output projection
    gemm_bt<float, false><<<dim3(HDIM / 128, M_ROWS / 128), 256, 0, stream>>>(
        Ao, owb, nullptr, out, M_ROWS, HDIM, HDIM);
}

// Round 4
// 404.293 us; speedup vs baseline: 1.2694x; 1.2694x over previous
//
#include <hip/hip_runtime.h>
#include <stdint.h>

typedef unsigned short u16;
typedef float    f32x4  __attribute__((ext_vector_type(4)));
typedef __bf16   bf16x8 __attribute__((ext_vector_type(8)));
typedef u16      u16x8  __attribute__((ext_vector_type(8)));
typedef u16      u16x4  __attribute__((ext_vector_type(4)));
typedef float    f32x4v __attribute__((ext_vector_type(4)));

#define B_SZ   2
#define S_LEN  2048
#define HDIM   2048
#define NH_    16
#define NKV_   2
#define HD_    128
#define M_ROWS 4096   // B*S
#define NQKV   2560   // (NH + 2*NKV) * HD

static __device__ __forceinline__ u16 f2bf(float f) {
    uint32_t u = __builtin_bit_cast(uint32_t, f);
    uint32_t r = (u + 0x7fffu + ((u >> 16) & 1u)) >> 16;
    return (u16)r;
}
static __device__ __forceinline__ float bf2f(u16 b) {
    uint32_t u = ((uint32_t)b) << 16;
    return __builtin_bit_cast(float, u);
}
static __device__ __forceinline__ void gload_lds16(const void* g, void* l) {
    __builtin_amdgcn_global_load_lds((__attribute__((address_space(1))) void*)(g),
                                     (__attribute__((address_space(3))) void*)(l),
                                     16, 0, 0);
}

// ---------------- elementwise converts ----------------
__global__ void cvt_f32_bf16(const float* __restrict__ in, u16* __restrict__ out, int n4) {
    int i = blockIdx.x * blockDim.x + threadIdx.x;
    if (i >= n4) return;
    f32x4v v = ((const f32x4v*)in)[i];
    u16x4 o;
    o[0] = f2bf(v[0]); o[1] = f2bf(v[1]); o[2] = f2bf(v[2]); o[3] = f2bf(v[3]);
    ((u16x4*)out)[i] = o;
}

__global__ void concat_bias(const float* __restrict__ qb, const float* __restrict__ kb,
                            const float* __restrict__ vb, float* __restrict__ out) {
    int i = blockIdx.x * blockDim.x + threadIdx.x;
    if (i >= NQKV) return;
    if (i < 2048)       out[i] = qb[i];
    else if (i < 2304)  out[i] = kb[i - 2048];
    else                out[i] = vb[i - 2304];
}

__global__ void rope_table(float* __restrict__ tc, float* __restrict__ ts) {
    int p = blockIdx.x;
    int d = threadIdx.x;   // 64 threads
    float inv = expf(-(float)d * 0.14391156831212787f);
    float ang = (float)p * inv;
    float s, c;
    sincosf(ang, &s, &c);
    tc[p * 64 + d] = c;
    ts[p * 64 + d] = s;
}

// ---------------- GEMM: C[m,n] = sum_k A[m,k]*W[n,k] (+bias[n]) ----------------
template <typename OutT, bool HAS_BIAS>
__global__ __launch_bounds__(256) void gemm_bt(const u16* __restrict__ A,
                                               const u16* __restrict__ W,
                                               const float* __restrict__ bias,
                                               OutT* __restrict__ C,
                                               int M, int N, int K) {
    __shared__ u16 sA[128 * 32];
    __shared__ u16 sB[128 * 32];
    const int tid = threadIdx.x;
    const int lane = tid & 63;
    const int w = tid >> 6;
    const int wr = w >> 1, wc = w & 1;
    const int l15 = lane & 15, l4 = lane >> 4;
    const int brow = blockIdx.y * 128;
    const int bcol = blockIdx.x * 128;

    f32x4 acc[4][4];
#pragma unroll
    for (int m = 0; m < 4; ++m)
#pragma unroll
        for (int n = 0; n < 4; ++n) acc[m][n] = (f32x4){0.f, 0.f, 0.f, 0.f};

    const int nk = K >> 5;
    for (int kt = 0; kt < nk; ++kt) {
        __syncthreads();
#pragma unroll
        for (int i = 0; i < 2; ++i) {
            int e = i * 2048 + tid * 8;
            int row = e >> 5, col = e & 31;
            gload_lds16(A + (size_t)(brow + row) * K + kt * 32 + col, &sA[e]);
            gload_lds16(W + (size_t)(bcol + row) * K + kt * 32 + col, &sB[e]);
        }
        __syncthreads();
        bf16x8 af[4], bfr[4];
#pragma unroll
        for (int m = 0; m < 4; ++m)
            af[m] = *(const bf16x8*)&sA[(wr * 64 + m * 16 + l15) * 32 + l4 * 8];
#pragma unroll
        for (int n = 0; n < 4; ++n)
            bfr[n] = *(const bf16x8*)&sB[(wc * 64 + n * 16 + l15) * 32 + l4 * 8];
#pragma unroll
        for (int m = 0; m < 4; ++m)
#pragma unroll
            for (int n = 0; n < 4; ++n)
                acc[m][n] = __builtin_amdgcn_mfma_f32_16x16x32_bf16(af[m], bfr[n], acc[m][n], 0, 0, 0);
    }

#pragma unroll
    for (int m = 0; m < 4; ++m) {
#pragma unroll
        for (int n = 0; n < 4; ++n) {
            int cn = bcol + wc * 64 + n * 16 + l15;
            float bv = 0.f;
            if constexpr (HAS_BIAS) bv = bias[cn];
#pragma unroll
            for (int i = 0; i < 4; ++i) {
                int r = brow + wr * 64 + m * 16 + l4 * 4 + i;
                float v = acc[m][n][i] + bv;
                if constexpr (sizeof(OutT) == 2) {
                    C[(size_t)r * N + cn] = (OutT)f2bf(v);
                } else {
                    C[(size_t)r * N + cn] = v;
                }
            }
        }
    }
}

// ---------------- RoPE + layout ----------------
__global__ void rope_apply(const u16* __restrict__ qkv, const int* __restrict__ pos,
                           const float* __restrict__ tc, const float* __restrict__ ts,
                           u16* __restrict__ Qr, u16* __restrict__ Kr, u16* __restrict__ Vr) {
    int idx = blockIdx.x * blockDim.x + threadIdx.x;
    if (idx >= M_ROWS * 20 * 64) return;
    int d = idx & 63;
    int sec = (idx >> 6) % 20;
    int row = idx / (20 * 64);
    int b = row >> 11, s = row & 2047;
    int p = pos[row];
    const u16* q = qkv + (size_t)row * NQKV;
    if (sec < 16) {
        float c = tc[p * 64 + d], sn = ts[p * 64 + d];
        float x1 = bf2f(q[sec * 128 + d]);
        float x2 = bf2f(q[sec * 128 + d + 64]);
        size_t o = (((size_t)(b * NH_ + sec)) * S_LEN + s) * HD_ + d;
        Qr[o] = f2bf(x1 * c - x2 * sn);
        Qr[o + 64] = f2bf(x2 * c + x1 * sn);
    } else if (sec < 18) {
        int hk = sec - 16;
        float c = tc[p * 64 + d], sn = ts[p * 64 + d];
        float x1 = bf2f(q[2048 + hk * 128 + d]);
        float x2 = bf2f(q[2048 + hk * 128 + d + 64]);
        size_t o = (((size_t)(b * NKV_ + hk)) * S_LEN + s) * HD_ + d;
        Kr[o] = f2bf(x1 * c - x2 * sn);
        Kr[o + 64] = f2bf(x2 * c + x1 * sn);
    } else {
        int hv = sec - 18;
        size_t o = (((size_t)(b * NKV_ + hv)) * S_LEN + s) * HD_ + d;
        Vr[o] = q[2304 + hv * 128 + d];
        Vr[o + 64] = q[2304 + hv * 128 + d + 64];
    }
}

// ---------------- flash attention (causal, GQA) ----------------
// grid: (16, B*NH). Each block processes q-tiles {pair, 31-pair} (uniform 66 KV-tiles).
// 4 waves/block, 16 q-rows/wave, KV tile = 32. 2-phase double-buffered pipeline.
#define QB 64
#define KVB 32
#define VT_STRIDE 40   // padded: row stride 80B, PV reads 2-way (free)
__global__ __launch_bounds__(256) void attn_kernel(const u16* __restrict__ Qr,
                                                   const u16* __restrict__ Kr,
                                                   const u16* __restrict__ Vr,
                                                   u16* __restrict__ Ao) {
    __shared__ u16 sK[2][KVB * HD_];         // XOR-swizzled rows [key][d]
    __shared__ u16 sVt[2][HD_ * VT_STRIDE];  // transposed [d][key], padded stride
    __shared__ u16 sP[4][16 * KVB];          // per-wave P tile

    const int tid = threadIdx.x;
    const int lane = tid & 63;
    const int w = tid >> 6;
    const int l15 = lane & 15;
    const int l4 = lane >> 4;

    const int bh = blockIdx.y;
    const int b = bh >> 4;
    const int h = bh & 15;
    const int kvh = h >> 3;
    const size_t kvbase = ((size_t)(b * NKV_ + kvh)) * S_LEN * HD_;

    // K staging mapping (pre-swizzled global source, linear LDS dest)
    int kg_off[2], kl_off[2];
#pragma unroll
    for (int i = 0; i < 2; ++i) {
        int e = i * 2048 + tid * 8;
        int L = e * 2;
        int key = L >> 8;
        int inner = (L & 255) ^ ((key & 7) << 4);
        kg_off[i] = key * HD_ + (inner >> 1);
        kl_off[i] = e;
    }
    // V staging mapping
    const int vkey = tid & 31;
    const int vd0 = (tid >> 5) * 16;

    const float scale = 0.08838834764831845f;  // 1/sqrt(128)

    for (int pass = 0; pass < 2; ++pass) {
        const int qbk = pass ? (31 - blockIdx.x) : blockIdx.x;
        const int qr0 = qbk * QB + w * 16;
        const size_t qbase = (((size_t)(b * NH_ + h)) * S_LEN + qr0 + l15) * HD_;
        bf16x8 qf[4];
#pragma unroll
        for (int c = 0; c < 4; ++c)
            qf[c] = *(const bf16x8*)(Qr + qbase + c * 32 + l4 * 8);

        f32x4 oa[8];
#pragma unroll
        for (int c = 0; c < 8; ++c) oa[c] = (f32x4){0.f, 0.f, 0.f, 0.f};
        float mrow[4], lrow[4];
#pragma unroll
        for (int i = 0; i < 4; ++i) { mrow[i] = -1e30f; lrow[i] = 0.f; }

        const int nt = 2 * qbk + 2;

        // ---- prologue: stage tile 0 into buffer 0 ----
        {
            const u16* kp = Kr + kvbase;
#pragma unroll
            for (int i = 0; i < 2; ++i) gload_lds16(kp + kg_off[i], &sK[0][kl_off[i]]);
            const u16* src = Vr + kvbase + (size_t)vkey * HD_ + vd0;
            u16x8 v0 = *(const u16x8*)(src);
            u16x8 v1 = *(const u16x8*)(src + 8);
#pragma unroll
            for (int j = 0; j < 8; ++j) sVt[0][(vd0 + j) * VT_STRIDE + vkey] = v0[j];
#pragma unroll
            for (int j = 0; j < 8; ++j) sVt[0][(vd0 + 8 + j) * VT_STRIDE + vkey] = v1[j];
        }
        __syncthreads();

        for (int t = 0; t < nt; ++t) {
            const int cur = t & 1;
            const int k0 = t * KVB;
            u16x8 v0n, v1n;
            const bool pre = (t + 1 < nt);
            if (pre) {
                // issue next-tile loads early (overlap with compute)
                const u16* kp = Kr + kvbase + (size_t)(k0 + KVB) * HD_;
#pragma unroll
                for (int i = 0; i < 2; ++i) gload_lds16(kp + kg_off[i], &sK[cur ^ 1][kl_off[i]]);
                const u16* src = Vr + kvbase + (size_t)(k0 + KVB + vkey) * HD_ + vd0;
                v0n = *(const u16x8*)(src);
                v1n = *(const u16x8*)(src + 8);
            }
            if (k0 <= qr0 + 15) {
                // QK^T -> 2 fragments of 16q x 16k
                f32x4 sf[2];
#pragma unroll
                for (int kt2 = 0; kt2 < 2; ++kt2) {
                    f32x4 f = (f32x4){0.f, 0.f, 0.f, 0.f};
#pragma unroll
                    for (int c = 0; c < 4; ++c) {
                        int key = kt2 * 16 + l15;
                        int addr = (key * 256 + c * 64 + l4 * 16) ^ ((key & 7) << 4);
                        bf16x8 kf = *(const bf16x8*)((const char*)sK[cur] + addr);
                        f = __builtin_amdgcn_mfma_f32_16x16x32_bf16(qf[c], kf, f, 0, 0, 0);
                    }
                    sf[kt2] = f;
                }
                // scale + causal mask + row max
                float pm[4];
#pragma unroll
                for (int i = 0; i < 4; ++i) pm[i] = -1e30f;
#pragma unroll
                for (int kt2 = 0; kt2 < 2; ++kt2) {
                    int kk = k0 + kt2 * 16 + l15;
#pragma unroll
                    for (int i = 0; i < 4; ++i) {
                        int qq = qr0 + l4 * 4 + i;
                        float v = sf[kt2][i] * scale;
                        v = (kk <= qq) ? v : -1e30f;
                        sf[kt2][i] = v;
                        pm[i] = fmaxf(pm[i], v);
                    }
                }
#pragma unroll
                for (int off = 1; off < 16; off <<= 1)
#pragma unroll
                    for (int i = 0; i < 4; ++i) pm[i] = fmaxf(pm[i], __shfl_xor(pm[i], off));
                float al[4], rs[4];
#pragma unroll
                for (int i = 0; i < 4; ++i) {
                    float mn = fmaxf(mrow[i], pm[i]);
                    al[i] = __expf(mrow[i] - mn);
                    mrow[i] = mn;
                }
#pragma unroll
                for (int kt2 = 0; kt2 < 2; ++kt2)
#pragma unroll
                    for (int i = 0; i < 4; ++i) sf[kt2][i] = __expf(sf[kt2][i] - mrow[i]);
#pragma unroll
                for (int i = 0; i < 4; ++i) rs[i] = sf[0][i] + sf[1][i];
#pragma unroll
                for (int off = 1; off < 16; off <<= 1)
#pragma unroll
                    for (int i = 0; i < 4; ++i) rs[i] += __shfl_xor(rs[i], off);
#pragma unroll
                for (int i = 0; i < 4; ++i) lrow[i] = lrow[i] * al[i] + rs[i];
#pragma unroll
                for (int c = 0; c < 8; ++c)
#pragma unroll
                    for (int i = 0; i < 4; ++i) oa[c][i] *= al[i];
                // P -> LDS (bf16)
#pragma unroll
                for (int kt2 = 0; kt2 < 2; ++kt2)
#pragma unroll
                    for (int i = 0; i < 4; ++i)
                        sP[w][(l4 * 4 + i) * KVB + kt2 * 16 + l15] = f2bf(sf[kt2][i]);
                // PV
                bf16x8 paf = *(const bf16x8*)&sP[w][l15 * KVB + l4 * 8];
#pragma unroll
                for (int c2 = 0; c2 < 8; ++c2) {
                    bf16x8 vf = *(const bf16x8*)&sVt[cur][(c2 * 16 + l15) * VT_STRIDE + l4 * 8];
                    oa[c2] = __builtin_amdgcn_mfma_f32_16x16x32_bf16(paf, vf, oa[c2], 0, 0, 0);
                }
            }
            if (pre) {
                // write next V tile (compiler inserts vmcnt wait on v0n/v1n)
#pragma unroll
                for (int j = 0; j < 8; ++j) sVt[cur ^ 1][(vd0 + j) * VT_STRIDE + vkey] = v0n[j];
#pragma unroll
                for (int j = 0; j < 8; ++j) sVt[cur ^ 1][(vd0 + 8 + j) * VT_STRIDE + vkey] = v1n[j];
            }
            __syncthreads();
        }

        // epilogue: divide by l, store to Ao[B*S, NH*HD]
#pragma unroll
        for (int i = 0; i < 4; ++i) {
            float inv = 1.0f / lrow[i];
            int qrow = qr0 + l4 * 4 + i;
            size_t rbase = ((size_t)(b * S_LEN) + qrow) * (size_t)(NH_ * HD_) + h * HD_;
#pragma unroll
            for (int c2 = 0; c2 < 8; ++c2)
                Ao[rbase + c2 * 16 + l15] = f2bf(oa[c2][i] * inv);
        }
    }
}

// ---------------- launch ----------------
extern "C" void kernel_launch(void* const* d_in, const int* in_sizes, int n_in,
                              void* d_out, int out_size, void* d_ws, size_t ws_size,
                              hipStream_t stream) {
    (void)in_sizes; (void)n_in; (void)out_size; (void)ws_size;
    const float* hs  = (const float*)d_in[0];
    const int*   pos = (const int*)d_in[1];
    const float* q_w = (const float*)d_in[2];
    const float* q_b = (const float*)d_in[3];
    const float* k_w = (const float*)d_in[4];
    const float* k_b = (const float*)d_in[5];
    const float* v_w = (const float*)d_in[6];
    const float* v_b = (const float*)d_in[7];
    const float* o_w = (const float*)d_in[8];
    float* out = (float*)d_out;

    char* ws = (char*)d_ws;
    u16* hsb = (u16*)ws;   ws += (size_t)M_ROWS * HDIM * 2;
    u16* wcat = (u16*)ws;  ws += (size_t)NQKV * HDIM * 2;
    u16* owb = (u16*)ws;   ws += (size_t)HDIM * HDIM * 2;
    float* bcat = (float*)ws; ws += (size_t)NQKV * 4;
    float* tc = (float*)ws;   ws += (size_t)S_LEN * 64 * 4;
    float* ts = (float*)ws;   ws += (size_t)S_LEN * 64 * 4;
    u16* qkv = (u16*)ws;   ws += (size_t)M_ROWS * NQKV * 2;
    u16* Kr = (u16*)ws;    ws += (size_t)B_SZ * NKV_ * S_LEN * HD_ * 2;
    u16* Vr = (u16*)ws;    ws += (size_t)B_SZ * NKV_ * S_LEN * HD_ * 2;
    u16* Qr = hsb;   // alias: hsb dead after QKV GEMM
    u16* Ao = qkv;   // alias: qkv dead after rope_apply

    cvt_f32_bf16<<<(M_ROWS * HDIM / 4 + 255) / 256, 256, 0, stream>>>(hs, hsb, M_ROWS * HDIM / 4);
    cvt_f32_bf16<<<(2048 * 2048 / 4 + 255) / 256, 256, 0, stream>>>(q_w, wcat, 2048 * 2048 / 4);
    cvt_f32_bf16<<<(256 * 2048 / 4 + 255) / 256, 256, 0, stream>>>(k_w, wcat + (size_t)2048 * 2048, 256 * 2048 / 4);
    cvt_f32_bf16<<<(256 * 2048 / 4 + 255) / 256, 256, 0, stream>>>(v_w, wcat + (size_t)2304 * 2048, 256 * 2048 / 4);
    cvt_f32_bf16<<<(2048 * 2048 / 4 + 255) / 256, 256, 0, stream>>>(o_w, owb, 2048 * 2048 / 4);
    concat_bias<<<(NQKV + 255) / 256, 256, 0, stream>>>(q_b, k_b, v_b, bcat);
    rope_table<<<S_LEN, 64, 0, stream>>>(tc, ts);

    gemm_bt<u16, true><<<dim3(NQKV / 128, M_ROWS / 128), 256, 0, stream>>>(
        hsb, wcat, bcat, qkv, M_ROWS, NQKV, HDIM);

    rope_apply<<<(M_ROWS * 20 * 64 + 255) / 256, 256, 0, stream>>>(qkv, pos, tc, ts, Qr, Kr, Vr);

    attn_kernel<<<dim3(16, B_SZ * NH_), 256, 0, stream>>>(Qr, Kr, Vr, Ao);

    gemm_bt<float, false><<<dim3(HDIM / 128, M_ROWS / 128), 256, 0, stream>>>(
        Ao, owb, nullptr, out, M_ROWS, HDIM, HDIM);
}